// Round 3
// baseline (65.371 us; speedup 1.0000x reference)
//
#include <hip/hip_runtime.h>
#include <math.h>

constexpr int Bdim = 32;
constexpr int Mdim = 8192;
constexpr int Idim = 256;
constexpr int ROWS_PER_BLOCK = 128;               // 4 waves x 32 rows
constexpr int ROWS_PER_WAVE = 32;                 // processed as 16 pairs
constexpr int NCHUNK = Mdim / ROWS_PER_BLOCK;     // 64 chunks per b

// ---------------------------------------------------------------------------
// 1) projected_key[b,i] = tanh(sum_k key[b,k] * W[i,k] + bias[i])
// ---------------------------------------------------------------------------
__global__ void proj_key_kernel(const float* __restrict__ key,
                                const float* __restrict__ W,
                                const float* __restrict__ bias,
                                float* __restrict__ pk) {
    int b = blockIdx.x;
    int i = threadIdx.x;
    __shared__ float kq[Idim];
    kq[i] = key[b * Idim + i];
    __syncthreads();
    const float4* w4 = (const float4*)(W + (size_t)i * Idim);
    const float4* k4 = (const float4*)kq;
    float s = bias[i];
    #pragma unroll 4
    for (int k = 0; k < Idim / 4; ++k) {
        float4 wv = w4[k];
        float4 kv = k4[k];
        s += wv.x * kv.x + wv.y * kv.y + wv.z * kv.z + wv.w * kv.w;
    }
    pk[b * Idim + i] = tanhf(s);
}

// ---------------------------------------------------------------------------
// 2) FUSED single pass over memory. Half-wave per row:
//    lanes 0-31 own row 2t, lanes 32-63 own row 2t+1; each lane covers 8
//    contiguous floats (32 B). 5-level shfl reduce within the half.
//    Online softmax with branch-guarded rescale (max rarely updates).
// ---------------------------------------------------------------------------
__global__ void fused_pass1_kernel(const float* __restrict__ memory,
                                   const float* __restrict__ pk,
                                   const float* __restrict__ beta,
                                   float* __restrict__ sim,
                                   float* __restrict__ pvec,
                                   float* __restrict__ pmx,
                                   float* __restrict__ psum) {
    int b = blockIdx.x / NCHUNK;
    int c = blockIdx.x % NCHUNK;
    int wave = threadIdx.x >> 6;
    int lane = threadIdx.x & 63;
    int half = lane >> 5;                       // which row of the pair
    int sub  = lane & 31;                       // position within the row
    float bt = beta[b];

    // this lane's 8 projected-key elements [sub*8, sub*8+8)
    const float4* pk4 = (const float4*)(pk + b * Idim);
    float4 pk0 = pk4[sub * 2];
    float4 pk1 = pk4[sub * 2 + 1];

    int row0 = c * ROWS_PER_BLOCK + wave * ROWS_PER_WAVE;
    const float* base = memory + ((size_t)b * Mdim + row0) * Idim;
    float* simp = sim + (size_t)b * Mdim + row0;

    float mx = -INFINITY, ssum = 0.f;
    float4 acc0 = make_float4(0.f, 0.f, 0.f, 0.f);
    float4 acc1 = make_float4(0.f, 0.f, 0.f, 0.f);
    float my_sim = 0.f;                         // lane w<32 keeps sim of row w

    for (int t = 0; t < ROWS_PER_WAVE / 2; ++t) {
        const float* rp = base + (size_t)(2 * t + half) * Idim + sub * 8;
        float4 m0 = *(const float4*)rp;
        float4 m1 = *(const float4*)(rp + 4);

        float d, s;
        d = pk0.x - m0.x; s  = d * d;
        d = pk0.y - m0.y; s += d * d;
        d = pk0.z - m0.z; s += d * d;
        d = pk0.w - m0.w; s += d * d;
        d = pk1.x - m1.x; s += d * d;
        d = pk1.y - m1.y; s += d * d;
        d = pk1.z - m1.z; s += d * d;
        d = pk1.w - m1.w; s += d * d;
        #pragma unroll
        for (int off = 16; off; off >>= 1) s += __shfl_xor(s, off, 64);
        // all lanes of a half now hold their row's full distance
        float s_other = __shfl_xor(s, 32, 64);
        if ((lane >> 1) == t) my_sim = (lane & 1) ? -s_other : -s;

        float a = -bt * s;
        if (a > mx) {                           // rare after first few rows
            float scale = __expf(mx - a);       // exp(-inf)=0 handles t=0
            ssum *= scale;
            acc0.x *= scale; acc0.y *= scale; acc0.z *= scale; acc0.w *= scale;
            acc1.x *= scale; acc1.y *= scale; acc1.z *= scale; acc1.w *= scale;
            mx = a;
        }
        float p = __expf(a - mx);
        ssum += p;
        acc0.x = fmaf(p, m0.x, acc0.x);
        acc0.y = fmaf(p, m0.y, acc0.y);
        acc0.z = fmaf(p, m0.z, acc0.z);
        acc0.w = fmaf(p, m0.w, acc0.w);
        acc1.x = fmaf(p, m1.x, acc1.x);
        acc1.y = fmaf(p, m1.y, acc1.y);
        acc1.z = fmaf(p, m1.z, acc1.z);
        acc1.w = fmaf(p, m1.w, acc1.w);
    }
    if (lane < 32) simp[lane] = my_sim;         // coalesced 32-row sim store

    // combine the block's 8 wave-halves in LDS
    __shared__ float lacc[8][Idim];
    __shared__ float lmx[8], lsum[8];
    int wh = wave * 2 + half;
    ((float4*)(lacc[wh] + sub * 8))[0] = acc0;
    ((float4*)(lacc[wh] + sub * 8))[1] = acc1;
    if (sub == 0) { lmx[wh] = mx; lsum[wh] = ssum; }
    __syncthreads();

    float MX = lmx[0];
    #pragma unroll
    for (int h = 1; h < 8; ++h) MX = fmaxf(MX, lmx[h]);
    float e[8];
    #pragma unroll
    for (int h = 0; h < 8; ++h) e[h] = __expf(lmx[h] - MX);

    int i = threadIdx.x;
    float v = 0.f;
    #pragma unroll
    for (int h = 0; h < 8; ++h) v += lacc[h][i] * e[h];
    size_t pc = (size_t)b * NCHUNK + c;
    pvec[pc * Idim + i] = v;
    if (threadIdx.x == 0) {
        float sc = 0.f;
        #pragma unroll
        for (int h = 0; h < 8; ++h) sc += lsum[h] * e[h];
        pmx[pc] = MX;
        psum[pc] = sc;
    }
}

// ---------------------------------------------------------------------------
// 3) per-b: combine 64 chunk partials -> read_vector; then produce weights
//    from the already-stored sim using the just-computed MX and 1/S.
// ---------------------------------------------------------------------------
__global__ void combine_weights_kernel(const float* __restrict__ pvec,
                                       const float* __restrict__ pmx,
                                       const float* __restrict__ psum,
                                       const float* __restrict__ sim,
                                       const float* __restrict__ beta,
                                       float* __restrict__ read_vec,
                                       float* __restrict__ weights) {
    int b = blockIdx.x;
    int tid = threadIdx.x;
    __shared__ float e[NCHUNK];
    __shared__ float MXs, sInvs;

    if (tid < NCHUNK) {                         // wave 0 handles the scalars
        float m = pmx[(size_t)b * NCHUNK + tid];
        float mm = m;
        #pragma unroll
        for (int off = 32; off; off >>= 1) mm = fmaxf(mm, __shfl_xor(mm, off, 64));
        float ec = __expf(m - mm);
        e[tid] = ec;
        float sc = psum[(size_t)b * NCHUNK + tid] * ec;
        #pragma unroll
        for (int off = 32; off; off >>= 1) sc += __shfl_xor(sc, off, 64);
        if (tid == 0) { MXs = mm; sInvs = 1.f / sc; }
    }
    __syncthreads();

    float MX = MXs, inv = sInvs;

    // read_vector
    float v = 0.f;
    const float* p = pvec + (size_t)b * NCHUNK * Idim + tid;
    #pragma unroll 8
    for (int c = 0; c < NCHUNK; ++c) v += p[(size_t)c * Idim] * e[c];
    read_vec[(size_t)b * Idim + tid] = v * inv;

    // weights[b,m] = exp(bt*sim - MX) * inv   (8192 elems, float4, 8 iters)
    float bt = beta[b];
    const float4* s4 = (const float4*)(sim + (size_t)b * Mdim);
    float4* w4 = (float4*)(weights + (size_t)b * Mdim);
    for (int m4 = tid; m4 < Mdim / 4; m4 += 256) {
        float4 s = s4[m4];
        float4 w;
        w.x = __expf(bt * s.x - MX) * inv;
        w.y = __expf(bt * s.y - MX) * inv;
        w.z = __expf(bt * s.z - MX) * inv;
        w.w = __expf(bt * s.w - MX) * inv;
        w4[m4] = w;
    }
}

extern "C" void kernel_launch(void* const* d_in, const int* in_sizes, int n_in,
                              void* d_out, int out_size, void* d_ws, size_t ws_size,
                              hipStream_t stream) {
    const float* memory = (const float*)d_in[0];   // [B, M, I]
    const float* key    = (const float*)d_in[1];   // [B, I]
    const float* beta   = (const float*)d_in[2];   // [B]
    const float* W      = (const float*)d_in[3];   // [I, I]
    const float* bias   = (const float*)d_in[4];   // [I]

    float* out = (float*)d_out;
    float* weights  = out;                                     // [B, M]
    float* read_vec = out + (size_t)Bdim * Mdim;               // [B, I]
    float* sim      = read_vec + (size_t)Bdim * Idim;          // [B, M]

    float* pk   = (float*)d_ws;                                // [B, I]
    float* pvec = pk + (size_t)Bdim * Idim;                    // [B, NCHUNK, I]
    float* pmx  = pvec + (size_t)Bdim * NCHUNK * Idim;         // [B, NCHUNK]
    float* psum = pmx + (size_t)Bdim * NCHUNK;                 // [B, NCHUNK]

    proj_key_kernel<<<Bdim, Idim, 0, stream>>>(key, W, bias, pk);
    fused_pass1_kernel<<<Bdim * NCHUNK, 256, 0, stream>>>(memory, pk, beta,
                                                          sim, pvec, pmx, psum);
    combine_weights_kernel<<<Bdim, 256, 0, stream>>>(pvec, pmx, psum, sim, beta,
                                                     read_vec, weights);
}